// Round 5
// baseline (120.702 us; speedup 1.0000x reference)
//
#include <hip/hip_runtime.h>
#include <hip/hip_bf16.h>

// Problem constants (from reference setup_inputs)
#define RR 3
#define BB 2
#define NN 2048
#define DD 128
#define HH 4
#define HD 32
#define LEAKY 0.2f
#define LN_EPS 1e-5f
#define LOG2E 1.4426950408889634f

using f32x4  = __attribute__((ext_vector_type(4))) float;
using bf16x8 = __attribute__((ext_vector_type(8))) short;

__device__ __forceinline__ float leakyf(float x) { return fmaxf(x, LEAKY * x); }

// ---------------------------------------------------------------------------
// Kernel 0: compact A (int32 0/1, 100.7 MB) -> bitmask (3.1 MB).
// Pure streaming read; mandatory-input-BW floor (~17 us at 6 TB/s).
// ---------------------------------------------------------------------------
__global__ __launch_bounds__(256) void compact_kernel(
    const int* __restrict__ A, unsigned* __restrict__ bm)
{
    const long g = (long)blockIdx.x * 256 + threadIdx.x;   // word index
    const int4* p = (const int4*)(A + g * 32);
    unsigned w = 0;
#pragma unroll
    for (int k = 0; k < 8; ++k) {
        int4 v = p[k];
        w |= (v.x != 0 ? 1u : 0u) << (k * 4 + 0);
        w |= (v.y != 0 ? 1u : 0u) << (k * 4 + 1);
        w |= (v.z != 0 ? 1u : 0u) << (k * 4 + 2);
        w |= (v.w != 0 ? 1u : 0u) << (k * 4 + 3);
    }
    bm[g] = w;
}

// ---------------------------------------------------------------------------
// Kernel 1: Wh = H @ W per (r,b,h); store Wh^T bf16 [rbh][f][n]; e_src/e_dst
// pre-scaled by log2(e). grid = R*B*HH*(N/64) = 768 blocks.
// ---------------------------------------------------------------------------
__global__ __launch_bounds__(256) void wh_kernel(
    const float* __restrict__ H, const float* __restrict__ W,
    const float* __restrict__ a_src, const float* __restrict__ a_dst,
    float* __restrict__ es, float* __restrict__ ed,
    __hip_bfloat16* __restrict__ whT)
{
    const int bid = blockIdx.x;
    const int nt = bid & 31;
    const int h  = (bid >> 5) & 3;
    const int b  = (bid >> 7) & 1;
    const int r  = bid >> 8;
    const int n0 = nt << 6;
    const int t  = threadIdx.x;

    __shared__ __align__(16) float Hs[64 * 128];
    __shared__ __align__(16) float Ws[128 * 32];

    const float* Hb = H + ((long)b * NN + n0) * DD;
#pragma unroll
    for (int k = 0; k < 8; ++k) {
        int f4 = t + 256 * k;
        ((float4*)Hs)[f4] = ((const float4*)Hb)[f4];
    }
    const float* Wb = W + (long)(r * HH + h) * DD * HD;
#pragma unroll
    for (int k = 0; k < 4; ++k) {
        int f4 = t + 256 * k;
        ((float4*)Ws)[f4] = ((const float4*)Wb)[f4];
    }
    __syncthreads();

    const int f  = t & 31;
    const int rg = t >> 5;
    const float av = a_src[(r * HH + h) * HD + f] * LOG2E;
    const float dv = a_dst[(r * HH + h) * HD + f] * LOG2E;
    const int rbh = (r * BB + b) * HH + h;

#pragma unroll
    for (int k = 0; k < 8; ++k) {
        const int row = rg * 8 + k;
        const float4* hrow = (const float4*)&Hs[row * 128];
        float acc = 0.0f;
#pragma unroll
        for (int d4 = 0; d4 < 32; ++d4) {
            float4 hv = hrow[d4];
            acc += hv.x * Ws[(d4 * 4 + 0) * 32 + f];
            acc += hv.y * Ws[(d4 * 4 + 1) * 32 + f];
            acc += hv.z * Ws[(d4 * 4 + 2) * 32 + f];
            acc += hv.w * Ws[(d4 * 4 + 3) * 32 + f];
        }
        whT[((long)rbh * HD + f) * NN + n0 + row] = __float2bfloat16(acc);
        float s = acc * av;
        float d = acc * dv;
#pragma unroll
        for (int m = 1; m < 32; m <<= 1) {
            s += __shfl_xor(s, m);
            d += __shfl_xor(d, m);
        }
        if (f == 0) {
            es[(long)rbh * NN + n0 + row] = s;
            ed[(long)rbh * NN + n0 + row] = d;
        }
    }
}

// ---------------------------------------------------------------------------
// Kernel 1b: med[rbh] = max_j e_dst[rbh][j]
// ---------------------------------------------------------------------------
__global__ __launch_bounds__(256) void med_kernel(
    const float* __restrict__ ed, float* __restrict__ med)
{
    const int rbh = blockIdx.x;
    const int t = threadIdx.x;
    const float* e = ed + (long)rbh * NN;
    float m = -1e30f;
    for (int k = t; k < NN; k += 256) m = fmaxf(m, e[k]);
#pragma unroll
    for (int s = 1; s < 64; s <<= 1) m = fmaxf(m, __shfl_xor(m, s));
    __shared__ float red[4];
    if ((t & 63) == 0) red[t >> 6] = m;
    __syncthreads();
    if (t == 0) med[rbh] = fmaxf(fmaxf(red[0], red[1]), fmaxf(red[2], red[3]));
}

// ---------------------------------------------------------------------------
// Kernel 2: fused masked softmax + MFMA aggregation, j-split by JS for
// occupancy. Writes UN-normalized numerators + per-(row,head) denominators;
// division happens in finalize (needs the full-j denominator).
// grid = R*B*(N/16)*JS blocks (XCD-chunk swizzled), 256 threads (4 waves=heads).
// ---------------------------------------------------------------------------
template<int JS>
__global__ __launch_bounds__(256, 6) void gat_attn_kernel(
    const unsigned* __restrict__ bm, const float* __restrict__ es,
    const float* __restrict__ ed, const float* __restrict__ med,
    const __hip_bfloat16* __restrict__ whT,
    float* __restrict__ num, float* __restrict__ den)
{
    constexpr int JQ = NN / JS;            // j-range per block
    const int nwg = RR * BB * 128 * JS;
    // XCD-chunked bijective swizzle (nwg % 8 == 0): each XCD gets a
    // contiguous logical range -> (r,b) panel stays in its L2.
    const int lg = (blockIdx.x % 8) * (nwg / 8) + blockIdx.x / 8;
    const int jh = lg % JS;
    const int it = (lg / JS) & 127;
    const int b  = (lg / (JS * 128)) % BB;
    const int r  = lg / (JS * 128 * BB);
    const int i0 = it << 4;
    const int tid = threadIdx.x;
    const int h = tid >> 6;               // wave = head
    const int l = tid & 63;
    const int row = l & 15;               // A-frag row (= B-frag f-row)
    const int kg  = l >> 4;               // k-octet 0..3

    const int rbh = (r * BB + b) * HH + h;
    const float esv = es[(long)rbh * NN + i0 + row];     // log2e-scaled
    const float M   = leakyf(esv + med[rbh]);            // exact row-max bound
    const float esvM   = esv - M;                        // for x>0 branch
    const float esv02M = fmaf(LEAKY, esv, -M);           // for x<0 branch

    const unsigned* bmp = bm + ((((long)(r * BB + b) * NN + i0 + row) * NN) >> 5)
                             + jh * (JQ / 32);
    const float4* Ep = (const float4*)(ed + (long)rbh * NN + jh * JQ + kg * 8);
    const __hip_bfloat16* w0 = whT + (long)rbh * HD * NN + (long)row * NN + jh * JQ + kg * 8;
    const __hip_bfloat16* w1 = w0 + 16 * NN;

    f32x4 acc0 = {0.f, 0.f, 0.f, 0.f};
    f32x4 acc1 = {0.f, 0.f, 0.f, 0.f};
    f32x4 accD = {0.f, 0.f, 0.f, 0.f};
    bf16x8 ones;
#pragma unroll
    for (int i = 0; i < 8; ++i) ones[i] = (short)0x3F80;  // bf16 1.0

#pragma unroll 2
    for (int jc = 0; jc < JQ / 32; ++jc) {
        unsigned mword = bmp[jc];
        float4 e0 = Ep[jc * 8];
        float4 e1 = Ep[jc * 8 + 1];
        const unsigned myb = (mword >> (kg * 8)) & 0xffu;

        float ev[8];
        ev[0] = e0.x; ev[1] = e0.y; ev[2] = e0.z; ev[3] = e0.w;
        ev[4] = e1.x; ev[5] = e1.y; ev[6] = e1.z; ev[7] = e1.w;

        bf16x8 pfrag;
#pragma unroll
        for (int c = 0; c < 8; ++c) {
            float u = esvM + ev[c];                      // x - M (x>0 branch)
            float v = fmaf(LEAKY, ev[c], esv02M);        // 0.2x - M
            float p = __builtin_amdgcn_exp2f(fmaxf(u, v));
            p *= (float)((myb >> c) & 1u);               // mask
            __hip_bfloat16 hb = __float2bfloat16(p);
            pfrag[c] = __builtin_bit_cast(short, hb);
        }

        bf16x8 b0 = *(const bf16x8*)(w0 + (long)jc * 32);
        bf16x8 b1 = *(const bf16x8*)(w1 + (long)jc * 32);

        acc0 = __builtin_amdgcn_mfma_f32_16x16x32_bf16(pfrag, b0, acc0, 0, 0, 0);
        acc1 = __builtin_amdgcn_mfma_f32_16x16x32_bf16(pfrag, b1, acc1, 0, 0, 0);
        accD = __builtin_amdgcn_mfma_f32_16x16x32_bf16(pfrag, ones, accD, 0, 0, 0);
    }

    // epilogue: write un-normalized numerator + denominator
    const int fcol = l & 15;
#pragma unroll
    for (int reg = 0; reg < 4; ++reg) {
        const int orow = (l >> 4) * 4 + reg;
        const long ro = (long)(r * JS + jh) * (BB * NN) + (long)b * NN + i0 + orow;
        num[ro * DD + h * HD + fcol]      = acc0[reg];
        num[ro * DD + h * HD + 16 + fcol] = acc1[reg];
        if (fcol == 0) den[ro * HH + h] = accD[reg];   // same value in 16 lanes
    }
}

// ---------------------------------------------------------------------------
// Kernel 3: out = LayerNorm(H + mean_r (num_r / den_r)).  One wave per row.
// ---------------------------------------------------------------------------
__global__ __launch_bounds__(256) void finalize_kernel(
    const float* __restrict__ H, const float* __restrict__ num,
    const float* __restrict__ den,
    const float* __restrict__ gamma, const float* __restrict__ beta,
    float* __restrict__ out, int js)
{
    const int w = threadIdx.x >> 6;
    const int l = threadIdx.x & 63;
    const long row = (long)blockIdx.x * 4 + w;    // over B*N rows
    const float2 hv = ((const float2*)(H + row * DD))[l];

    float ax = 0.f, ay = 0.f;
    for (int r = 0; r < RR; ++r) {
        float dsum = 0.f, nx = 0.f, ny = 0.f;
        for (int j = 0; j < js; ++j) {
            const long ro = (long)(r * js + j) * (BB * NN) + row;
            dsum += den[ro * HH + (l >> 4)];
            const float2 nv = ((const float2*)(num + ro * DD))[l];
            nx += nv.x; ny += nv.y;
        }
        const float inv = (dsum > 0.f) ? 1.0f / dsum : 0.0f;
        ax = fmaf(nx, inv, ax);
        ay = fmaf(ny, inv, ay);
    }
    const float x0 = hv.x + ax * (1.0f / RR);
    const float x1 = hv.y + ay * (1.0f / RR);
    float s = x0 + x1, q = x0 * x0 + x1 * x1;
#pragma unroll
    for (int m = 1; m < 64; m <<= 1) {
        s += __shfl_xor(s, m);
        q += __shfl_xor(q, m);
    }
    const float mu  = s * (1.0f / DD);
    const float var = q * (1.0f / DD) - mu * mu;
    const float inv = rsqrtf(var + LN_EPS);
    const float g0 = gamma[l * 2], g1 = gamma[l * 2 + 1];
    const float b0 = beta[l * 2],  b1 = beta[l * 2 + 1];
    float2 o;
    o.x = (x0 - mu) * inv * g0 + b0;
    o.y = (x1 - mu) * inv * g1 + b1;
    ((float2*)(out + row * DD))[l] = o;
}

// ---------------------------------------------------------------------------
extern "C" void kernel_launch(void* const* d_in, const int* in_sizes, int n_in,
                              void* d_out, int out_size, void* d_ws, size_t ws_size,
                              hipStream_t stream)
{
    const float* H      = (const float*)d_in[0];
    const int*   A      = (const int*)d_in[1];
    const float* W      = (const float*)d_in[2];
    const float* a_src  = (const float*)d_in[3];
    const float* a_dst  = (const float*)d_in[4];
    const float* gamma  = (const float*)d_in[5];
    const float* beta   = (const float*)d_in[6];
    float* out = (float*)d_out;

    // pick j-split factor that fits the workspace
    const size_t fixed = (size_t)RR * BB * HH * NN * 4 * 2   // es + ed
                       + 256                                  // med
                       + (size_t)RR * BB * HH * HD * NN * 2   // whT
                       + (size_t)RR * BB * NN * (NN / 32) * 4;// bitmask
    auto need = [&](int js) {
        return fixed + (size_t)RR * js * BB * NN * (DD + HH) * 4; // num + den
    };
    const int js = (ws_size >= need(2)) ? 2 : 1;

    char* ws = (char*)d_ws;
    float* num = (float*)ws;                     ws += (size_t)RR * js * BB * NN * DD * 4;
    float* den = (float*)ws;                     ws += (size_t)RR * js * BB * NN * HH * 4;
    float* es  = (float*)ws;                     ws += (size_t)RR * BB * HH * NN * 4;
    float* ed  = (float*)ws;                     ws += (size_t)RR * BB * HH * NN * 4;
    float* med = (float*)ws;                     ws += 256;
    __hip_bfloat16* whT = (__hip_bfloat16*)ws;   ws += (size_t)RR * BB * HH * HD * NN * 2;
    unsigned* bmask = (unsigned*)ws;             ws += (size_t)RR * BB * NN * (NN / 32) * 4;

    compact_kernel<<<RR * BB * NN * (NN / 32) / 256, 256, 0, stream>>>(A, bmask);
    wh_kernel<<<RR * BB * HH * (NN / 64), 256, 0, stream>>>(H, W, a_src, a_dst, es, ed, whT);
    med_kernel<<<RR * BB * HH, 256, 0, stream>>>(ed, med);
    if (js == 2) {
        gat_attn_kernel<2><<<RR * BB * 128 * 2, 256, 0, stream>>>(bmask, es, ed, med, whT, num, den);
    } else {
        gat_attn_kernel<1><<<RR * BB * 128 * 1, 256, 0, stream>>>(bmask, es, ed, med, whT, num, den);
    }
    finalize_kernel<<<BB * NN / 4, 256, 0, stream>>>(H, num, den, gamma, beta, out, js);
}

// Round 6
// 88.595 us; speedup vs baseline: 1.3624x; 1.3624x over previous
//
#include <hip/hip_runtime.h>
#include <hip/hip_bf16.h>

// Problem constants (from reference setup_inputs)
#define RR 3
#define BB 2
#define NN 2048
#define DD 128
#define HH 4
#define HD 32
#define LEAKY 0.2f
#define LN_EPS 1e-5f
#define LOG2E 1.4426950408889634f

using f32x4  = __attribute__((ext_vector_type(4))) float;
using bf16x8 = __attribute__((ext_vector_type(8))) short;

__device__ __forceinline__ float leakyf(float x) { return fmaxf(x, LEAKY * x); }

__device__ __forceinline__ void gload_lds16(const void* g, void* l) {
    __builtin_amdgcn_global_load_lds(
        (const __attribute__((address_space(1))) unsigned*)g,
        (__attribute__((address_space(3))) unsigned*)l, 16, 0, 0);
}
__device__ __forceinline__ void gload_lds4(const void* g, void* l) {
    __builtin_amdgcn_global_load_lds(
        (const __attribute__((address_space(1))) unsigned*)g,
        (__attribute__((address_space(3))) unsigned*)l, 4, 0, 0);
}

// ---------------------------------------------------------------------------
// Kernel 0: compact A (int32 0/1, 100.7 MB) -> bitmask (3.1 MB).
// Pure streaming read; mandatory-input-BW floor (~17 us at 6 TB/s).
// ---------------------------------------------------------------------------
__global__ __launch_bounds__(256) void compact_kernel(
    const int* __restrict__ A, unsigned* __restrict__ bm)
{
    const long g = (long)blockIdx.x * 256 + threadIdx.x;   // word index
    const int4* p = (const int4*)(A + g * 32);
    unsigned w = 0;
#pragma unroll
    for (int k = 0; k < 8; ++k) {
        int4 v = p[k];
        w |= (v.x != 0 ? 1u : 0u) << (k * 4 + 0);
        w |= (v.y != 0 ? 1u : 0u) << (k * 4 + 1);
        w |= (v.z != 0 ? 1u : 0u) << (k * 4 + 2);
        w |= (v.w != 0 ? 1u : 0u) << (k * 4 + 3);
    }
    bm[g] = w;
}

// ---------------------------------------------------------------------------
// Kernel 1: Wh = H @ W per (r,b,h); store Wh^T bf16 [rbh][f][n]; e_src/e_dst
// pre-scaled by log2(e). grid = R*B*HH*(N/64) = 768 blocks.
// ---------------------------------------------------------------------------
__global__ __launch_bounds__(256) void wh_kernel(
    const float* __restrict__ H, const float* __restrict__ W,
    const float* __restrict__ a_src, const float* __restrict__ a_dst,
    float* __restrict__ es, float* __restrict__ ed,
    __hip_bfloat16* __restrict__ whT)
{
    const int bid = blockIdx.x;
    const int nt = bid & 31;
    const int h  = (bid >> 5) & 3;
    const int b  = (bid >> 7) & 1;
    const int r  = bid >> 8;
    const int n0 = nt << 6;
    const int t  = threadIdx.x;

    __shared__ __align__(16) float Hs[64 * 128];
    __shared__ __align__(16) float Ws[128 * 32];

    const float* Hb = H + ((long)b * NN + n0) * DD;
#pragma unroll
    for (int k = 0; k < 8; ++k) {
        int f4 = t + 256 * k;
        ((float4*)Hs)[f4] = ((const float4*)Hb)[f4];
    }
    const float* Wb = W + (long)(r * HH + h) * DD * HD;
#pragma unroll
    for (int k = 0; k < 4; ++k) {
        int f4 = t + 256 * k;
        ((float4*)Ws)[f4] = ((const float4*)Wb)[f4];
    }
    __syncthreads();

    const int f  = t & 31;
    const int rg = t >> 5;
    const float av = a_src[(r * HH + h) * HD + f] * LOG2E;
    const float dv = a_dst[(r * HH + h) * HD + f] * LOG2E;
    const int rbh = (r * BB + b) * HH + h;

#pragma unroll
    for (int k = 0; k < 8; ++k) {
        const int row = rg * 8 + k;
        const float4* hrow = (const float4*)&Hs[row * 128];
        float acc = 0.0f;
#pragma unroll
        for (int d4 = 0; d4 < 32; ++d4) {
            float4 hv = hrow[d4];
            acc += hv.x * Ws[(d4 * 4 + 0) * 32 + f];
            acc += hv.y * Ws[(d4 * 4 + 1) * 32 + f];
            acc += hv.z * Ws[(d4 * 4 + 2) * 32 + f];
            acc += hv.w * Ws[(d4 * 4 + 3) * 32 + f];
        }
        whT[((long)rbh * HD + f) * NN + n0 + row] = __float2bfloat16(acc);
        float s = acc * av;
        float d = acc * dv;
#pragma unroll
        for (int m = 1; m < 32; m <<= 1) {
            s += __shfl_xor(s, m);
            d += __shfl_xor(d, m);
        }
        if (f == 0) {
            es[(long)rbh * NN + n0 + row] = s;
            ed[(long)rbh * NN + n0 + row] = d;
        }
    }
}

// ---------------------------------------------------------------------------
// Kernel 1b: med[rbh] = max_j e_dst[rbh][j]
// ---------------------------------------------------------------------------
__global__ __launch_bounds__(256) void med_kernel(
    const float* __restrict__ ed, float* __restrict__ med)
{
    const int rbh = blockIdx.x;
    const int t = threadIdx.x;
    const float* e = ed + (long)rbh * NN;
    float m = -1e30f;
    for (int k = t; k < NN; k += 256) m = fmaxf(m, e[k]);
#pragma unroll
    for (int s = 1; s < 64; s <<= 1) m = fmaxf(m, __shfl_xor(m, s));
    __shared__ float red[4];
    if ((t & 63) == 0) red[t >> 6] = m;
    __syncthreads();
    if (t == 0) med[rbh] = fmaxf(fmaxf(red[0], red[1]), fmaxf(red[2], red[3]));
}

// ---------------------------------------------------------------------------
// Kernel 2: fused masked softmax + MFMA aggregation, LDS-staged.
// block = (r, b, head, 64-i-rows, j-half of 1024); 4 waves = 4 i-subtiles
// sharing the head's whT panel. 8 double-buffered stages of 128 j each,
// staged via global_load_lds (counted vmcnt -> loads in flight across
// barriers). Inner loop touches LDS only (fragment-ordered, conflict-free).
// grid = R*B*HH*32*2 = 1536 blocks (XCD-chunk swizzled), 256 threads.
// ---------------------------------------------------------------------------
__global__ __launch_bounds__(256, 6) void gat_attn_kernel(
    const unsigned* __restrict__ bm, const float* __restrict__ es,
    const float* __restrict__ ed, const float* __restrict__ med,
    const __hip_bfloat16* __restrict__ whT,
    float* __restrict__ num, float* __restrict__ den)
{
    // XCD-chunked bijective swizzle (1536 % 8 == 0)
    const int lg = ((int)blockIdx.x % 8) * (RR * BB * HH * 32 * 2 / 8) + (int)blockIdx.x / 8;
    const int jh = lg & 1;                 // j-half
    const int it = (lg >> 1) & 31;         // i-tile (64 rows)
    const int h  = (lg >> 6) & 3;
    const int b  = (lg >> 8) & 1;
    const int r  = lg >> 9;
    const int i0 = it << 6;
    const int tid = threadIdx.x;
    const int w = tid >> 6;                // wave = i-subtile (16 rows)
    const int l = tid & 63;
    const int row = l & 15;                // P-row within wave / B-frag f-row
    const int kg  = l >> 4;                // k-octet 0..3

    // LDS staging buffers (double-buffered): 19 KB total
    __shared__ __align__(16) short    whs[2][4][4][32][8]; // [buf][jc][kg][f][8bf16]
    __shared__ __align__(16) unsigned bms[2][4][64];       // [buf][jc][i-row 0..63]
    __shared__ __align__(16) float    eds[2][4][4][8];     // [buf][jc][kg][e]

    const int rbh = (r * BB + b) * HH + h;
    const long rbNN = (long)(r * BB + b) * NN;
    const __hip_bfloat16* whTr = whT + (long)rbh * HD * NN;
    const float* edr = ed + (long)rbh * NN;
    const int jbase = jh * (NN / 2);

    // per-row softmax constants (resolve BEFORE staging loop; pin with asm)
    const float esv = es[(long)rbh * NN + i0 + w * 16 + row];  // log2e-scaled
    const float M   = leakyf(esv + med[rbh]);                  // exact row-max bound
    const float esvM   = esv - M;
    const float esv02M = fmaf(LEAKY, esv, -M);
    asm volatile("" :: "v"(esvM), "v"(esv02M));

    const int f31 = l & 31;
    const int kgr = l >> 5;

    // stage macro: wave w stages whT jc=w (2 halves), bm jc=w, ed 64-float chunk (w&1)
#define STAGE(s, nb) do {                                                          \
        const int j0s = jbase + (s) * 128;                                         \
        gload_lds16(whTr + (long)f31 * NN + j0s + w * 32 + (0 + kgr) * 8,          \
                    &whs[nb][w][0][0][0]);                                         \
        gload_lds16(whTr + (long)f31 * NN + j0s + w * 32 + (2 + kgr) * 8,          \
                    &whs[nb][w][2][0][0]);                                         \
        gload_lds4(bm + (rbNN + i0 + l) * (NN / 32) + (j0s >> 5) + w,              \
                   &bms[nb][w][0]);                                                \
        gload_lds4(edr + j0s + (w & 1) * 64 + l, &eds[nb][(w & 1) * 2][0][0]);     \
    } while (0)

    f32x4 acc0 = {0.f, 0.f, 0.f, 0.f};
    f32x4 acc1 = {0.f, 0.f, 0.f, 0.f};
    f32x4 accD = {0.f, 0.f, 0.f, 0.f};
    bf16x8 ones;
#pragma unroll
    for (int i = 0; i < 8; ++i) ones[i] = (short)0x3F80;  // bf16 1.0

    STAGE(0, 0);

    for (int s = 0; s < 8; ++s) {
        const int cb = s & 1, nb = cb ^ 1;
        if (s < 7) {
            STAGE(s + 1, nb);
            asm volatile("s_waitcnt vmcnt(4)" ::: "memory");
        } else {
            asm volatile("s_waitcnt vmcnt(0)" ::: "memory");
        }
        __builtin_amdgcn_sched_barrier(0);
        __syncthreads();

#pragma unroll
        for (int jc = 0; jc < 4; ++jc) {
            bf16x8 b0 = *(const bf16x8*)&whs[cb][jc][kg][row][0];
            bf16x8 b1 = *(const bf16x8*)&whs[cb][jc][kg][row + 16][0];
            float4 e0 = *(const float4*)&eds[cb][jc][kg][0];
            float4 e1 = *(const float4*)&eds[cb][jc][kg][4];
            unsigned myb = (bms[cb][jc][w * 16 + row] >> (kg * 8)) & 0xffu;

            float ev[8];
            ev[0] = e0.x; ev[1] = e0.y; ev[2] = e0.z; ev[3] = e0.w;
            ev[4] = e1.x; ev[5] = e1.y; ev[6] = e1.z; ev[7] = e1.w;

            bf16x8 pfrag;
#pragma unroll
            for (int c = 0; c < 8; ++c) {
                float u = esvM + ev[c];                  // x - M (x>0 branch)
                float v = fmaf(LEAKY, ev[c], esv02M);    // 0.2x - M
                float p = __builtin_amdgcn_exp2f(fmaxf(u, v));
                p *= (float)((myb >> c) & 1u);           // mask
                __hip_bfloat16 hb = __float2bfloat16(p);
                pfrag[c] = __builtin_bit_cast(short, hb);
            }

            acc0 = __builtin_amdgcn_mfma_f32_16x16x32_bf16(pfrag, b0, acc0, 0, 0, 0);
            acc1 = __builtin_amdgcn_mfma_f32_16x16x32_bf16(pfrag, b1, acc1, 0, 0, 0);
            accD = __builtin_amdgcn_mfma_f32_16x16x32_bf16(pfrag, ones, accD, 0, 0, 0);
        }
        __syncthreads();
    }
#undef STAGE

    // epilogue: write un-normalized numerator + denominator
    const int fcol = l & 15;
    const int pr = r * 2 + jh;
#pragma unroll
    for (int reg = 0; reg < 4; ++reg) {
        const int orow = (l >> 4) * 4 + reg;
        const long ro = (long)pr * (BB * NN) + (long)b * NN + i0 + w * 16 + orow;
        num[ro * DD + h * HD + fcol]      = acc0[reg];
        num[ro * DD + h * HD + 16 + fcol] = acc1[reg];
        if (fcol == 0) den[ro * HH + h] = accD[reg];
    }
}

// ---------------------------------------------------------------------------
// Kernel 3: out = LayerNorm(H + mean_r (num_r / den_r)).  One wave per row.
// ---------------------------------------------------------------------------
__global__ __launch_bounds__(256) void finalize_kernel(
    const float* __restrict__ H, const float* __restrict__ num,
    const float* __restrict__ den,
    const float* __restrict__ gamma, const float* __restrict__ beta,
    float* __restrict__ out, int js)
{
    const int w = threadIdx.x >> 6;
    const int l = threadIdx.x & 63;
    const long row = (long)blockIdx.x * 4 + w;    // over B*N rows
    const float2 hv = ((const float2*)(H + row * DD))[l];

    float ax = 0.f, ay = 0.f;
    for (int r = 0; r < RR; ++r) {
        float dsum = 0.f, nx = 0.f, ny = 0.f;
        for (int j = 0; j < js; ++j) {
            const long ro = (long)(r * js + j) * (BB * NN) + row;
            dsum += den[ro * HH + (l >> 4)];
            const float2 nv = ((const float2*)(num + ro * DD))[l];
            nx += nv.x; ny += nv.y;
        }
        const float inv = (dsum > 0.f) ? 1.0f / dsum : 0.0f;
        ax = fmaf(nx, inv, ax);
        ay = fmaf(ny, inv, ay);
    }
    const float x0 = hv.x + ax * (1.0f / RR);
    const float x1 = hv.y + ay * (1.0f / RR);
    float s = x0 + x1, q = x0 * x0 + x1 * x1;
#pragma unroll
    for (int m = 1; m < 64; m <<= 1) {
        s += __shfl_xor(s, m);
        q += __shfl_xor(q, m);
    }
    const float mu  = s * (1.0f / DD);
    const float var = q * (1.0f / DD) - mu * mu;
    const float inv = rsqrtf(var + LN_EPS);
    const float g0 = gamma[l * 2], g1 = gamma[l * 2 + 1];
    const float b0 = beta[l * 2],  b1 = beta[l * 2 + 1];
    float2 o;
    o.x = (x0 - mu) * inv * g0 + b0;
    o.y = (x1 - mu) * inv * g1 + b1;
    ((float2*)(out + row * DD))[l] = o;
}

// ---------------------------------------------------------------------------
extern "C" void kernel_launch(void* const* d_in, const int* in_sizes, int n_in,
                              void* d_out, int out_size, void* d_ws, size_t ws_size,
                              hipStream_t stream)
{
    const float* H      = (const float*)d_in[0];
    const int*   A      = (const int*)d_in[1];
    const float* W      = (const float*)d_in[2];
    const float* a_src  = (const float*)d_in[3];
    const float* a_dst  = (const float*)d_in[4];
    const float* gamma  = (const float*)d_in[5];
    const float* beta   = (const float*)d_in[6];
    float* out = (float*)d_out;

    const int js = 2;  // j-halves produced by gat_attn

    char* ws = (char*)d_ws;
    float* num = (float*)ws;                     ws += (size_t)RR * js * BB * NN * DD * 4;
    float* den = (float*)ws;                     ws += (size_t)RR * js * BB * NN * HH * 4;
    float* es  = (float*)ws;                     ws += (size_t)RR * BB * HH * NN * 4;
    float* ed  = (float*)ws;                     ws += (size_t)RR * BB * HH * NN * 4;
    float* med = (float*)ws;                     ws += 256;
    __hip_bfloat16* whT = (__hip_bfloat16*)ws;   ws += (size_t)RR * BB * HH * HD * NN * 2;
    unsigned* bmask = (unsigned*)ws;             ws += (size_t)RR * BB * NN * (NN / 32) * 4;

    compact_kernel<<<RR * BB * NN * (NN / 32) / 256, 256, 0, stream>>>(A, bmask);
    wh_kernel<<<RR * BB * HH * (NN / 64), 256, 0, stream>>>(H, W, a_src, a_dst, es, ed, whT);
    med_kernel<<<RR * BB * HH, 256, 0, stream>>>(ed, med);
    gat_attn_kernel<<<RR * BB * HH * 32 * 2, 256, 0, stream>>>(bmask, es, ed, med, whT, num, den);
    finalize_kernel<<<BB * NN / 4, 256, 0, stream>>>(H, num, den, gamma, beta, out, js);
}

// Round 7
// 87.932 us; speedup vs baseline: 1.3727x; 1.0075x over previous
//
#include <hip/hip_runtime.h>
#include <hip/hip_bf16.h>

// Problem constants (from reference setup_inputs)
#define RR 3
#define BB 2
#define NN 2048
#define DD 128
#define HH 4
#define HD 32
#define LEAKY 0.2f
#define LN_EPS 1e-5f
#define LOG2E 1.4426950408889634f

using f32x4  = __attribute__((ext_vector_type(4))) float;
using bf16x8 = __attribute__((ext_vector_type(8))) short;

__device__ __forceinline__ void gload_lds16(const void* g, void* l) {
    __builtin_amdgcn_global_load_lds(
        (const __attribute__((address_space(1))) unsigned*)g,
        (__attribute__((address_space(3))) unsigned*)l, 16, 0, 0);
}
__device__ __forceinline__ void gload_lds4(const void* g, void* l) {
    __builtin_amdgcn_global_load_lds(
        (const __attribute__((address_space(1))) unsigned*)g,
        (__attribute__((address_space(3))) unsigned*)l, 4, 0, 0);
}

// ---------------------------------------------------------------------------
// Kernel 1: fused prep. 3840 blocks, 4:1 interleaved roles:
//  - 3072 "compact" blocks: A (100.7 MB int32) -> bitmask (3.1 MB). HBM-bound.
//  - 768  "wh" blocks: Wh = H@W per (r,b,h); whT bf16 [rbh][f][n]; es/ed
//    (log2e-scaled). VALU-bound; overlaps compact's BW time.
// ---------------------------------------------------------------------------
__global__ __launch_bounds__(256) void prep_kernel(
    const float* __restrict__ H, const int* __restrict__ A,
    const float* __restrict__ W,
    const float* __restrict__ a_src, const float* __restrict__ a_dst,
    float* __restrict__ es, float* __restrict__ ed,
    __hip_bfloat16* __restrict__ whT, unsigned* __restrict__ bm)
{
    __shared__ __align__(16) float Hs[64 * 128];
    __shared__ __align__(16) float Ws[128 * 32];

    const int g5 = blockIdx.x / 5, pos = blockIdx.x % 5;
    const int t  = threadIdx.x;

    if (pos < 4) {
        // ---- compact role ----
        const long gw = ((long)(g5 * 4 + pos)) * 256 + t;   // bitmask word index
        const int4* p = (const int4*)(A + gw * 32);
        unsigned wmask = 0;
#pragma unroll
        for (int k = 0; k < 8; ++k) {
            int4 v = p[k];
            wmask |= (v.x != 0 ? 1u : 0u) << (k * 4 + 0);
            wmask |= (v.y != 0 ? 1u : 0u) << (k * 4 + 1);
            wmask |= (v.z != 0 ? 1u : 0u) << (k * 4 + 2);
            wmask |= (v.w != 0 ? 1u : 0u) << (k * 4 + 3);
        }
        bm[gw] = wmask;
        return;
    }

    // ---- wh role ----
    const int bid = g5;               // 0..767
    const int nt = bid & 31;
    const int h  = (bid >> 5) & 3;
    const int b  = (bid >> 7) & 1;
    const int r  = bid >> 8;
    const int n0 = nt << 6;

    const float* Hb = H + ((long)b * NN + n0) * DD;
#pragma unroll
    for (int k = 0; k < 8; ++k) {
        int f4 = t + 256 * k;
        ((float4*)Hs)[f4] = ((const float4*)Hb)[f4];
    }
    const float* Wb = W + (long)(r * HH + h) * DD * HD;
#pragma unroll
    for (int k = 0; k < 4; ++k) {
        int f4 = t + 256 * k;
        ((float4*)Ws)[f4] = ((const float4*)Wb)[f4];
    }
    __syncthreads();

    const int f  = t & 31;
    const int rg = t >> 5;
    const float av = a_src[(r * HH + h) * HD + f] * LOG2E;
    const float dv = a_dst[(r * HH + h) * HD + f] * LOG2E;
    const int rbh = (r * BB + b) * HH + h;

#pragma unroll
    for (int k = 0; k < 8; ++k) {
        const int row = rg * 8 + k;
        const float4* hrow = (const float4*)&Hs[row * 128];
        float acc = 0.0f;
#pragma unroll
        for (int d4 = 0; d4 < 32; ++d4) {
            float4 hv = hrow[d4];
            acc += hv.x * Ws[(d4 * 4 + 0) * 32 + f];
            acc += hv.y * Ws[(d4 * 4 + 1) * 32 + f];
            acc += hv.z * Ws[(d4 * 4 + 2) * 32 + f];
            acc += hv.w * Ws[(d4 * 4 + 3) * 32 + f];
        }
        whT[((long)rbh * HD + f) * NN + n0 + row] = __float2bfloat16(acc);
        float s = acc * av;
        float d = acc * dv;
#pragma unroll
        for (int m = 1; m < 32; m <<= 1) {
            s += __shfl_xor(s, m);
            d += __shfl_xor(d, m);
        }
        if (f == 0) {
            es[(long)rbh * NN + n0 + row] = s;
            ed[(long)rbh * NN + n0 + row] = d;
        }
    }
}

// ---------------------------------------------------------------------------
// Kernel 2: fused masked softmax + MFMA aggregation.
// block = (r,b,h, 128 i-rows, j-half of 1024). 4 waves; each wave owns TWO
// 16-row i-subtiles (rows w*16 and 64+w*16) -> every staged whT/ed byte is
// used twice. 8 double-buffered stages of 128 j via global_load_lds with
// per-wave counted vmcnt(5) and RAW s_barrier (no compiler vmcnt(0) drain).
// Row-max bound computed in-kernel from ed (any upper bound cancels exactly).
// grid = R*B*HH*16*2 = 768 blocks (XCD-chunk swizzled), 256 threads.
// ---------------------------------------------------------------------------
__global__ __launch_bounds__(256, 3) void gat_attn_kernel(
    const unsigned* __restrict__ bm, const float* __restrict__ es,
    const float* __restrict__ ed, const __hip_bfloat16* __restrict__ whT,
    float* __restrict__ num, float* __restrict__ den)
{
    // XCD-chunked bijective swizzle (768 % 8 == 0)
    const int lg = ((int)blockIdx.x % 8) * 96 + (int)blockIdx.x / 8;
    const int jh = lg & 1;
    const int it = (lg >> 1) & 15;         // 16 tiles of 128 rows
    const int h  = (lg >> 5) & 3;
    const int b  = (lg >> 7) & 1;
    const int r  = lg >> 8;
    const int i0 = it << 7;
    const int tid = threadIdx.x;
    const int w = tid >> 6;
    const int l = tid & 63;
    const int row = l & 15;                // A-frag row / B-frag f-col
    const int kg  = l >> 4;                // k-octet
    const int f31 = l & 31;
    const int kgr = l >> 5;

    __shared__ __align__(16) short    whs[2][4][4][32][8]; // [buf][jc][kg][f][8] : 16 KB
    __shared__ __align__(16) unsigned bms[2][4][128];      // [buf][jc][blockrow] : 4 KB
    __shared__ __align__(16) float    eds[2][4][32];       // [buf][jc][j]        : 1 KB
    __shared__ float red[4];

    const int rbh = (r * BB + b) * HH + h;
    const long rbNN = (long)(r * BB + b) * NN;
    const __hip_bfloat16* whTr = whT + (long)rbh * HD * NN;
    const float* edr = ed + (long)rbh * NN;
    const int jbase = jh * (NN / 2);

#define STAGE(s, nb) do {                                                           \
        const int j0s = jbase + (s) * 128;                                          \
        gload_lds16(whTr + (long)f31 * NN + j0s + w * 32 + kgr * 8,                 \
                    &whs[nb][w][0][0][0]);                                          \
        gload_lds16(whTr + (long)f31 * NN + j0s + w * 32 + (2 + kgr) * 8,           \
                    &whs[nb][w][2][0][0]);                                          \
        gload_lds4(bm + (rbNN + i0 + l) * (NN / 32) + (j0s >> 5) + w,               \
                   &bms[nb][w][0]);                                                 \
        gload_lds4(bm + (rbNN + i0 + 64 + l) * (NN / 32) + (j0s >> 5) + w,          \
                   &bms[nb][w][64]);                                                \
        if (l < 32) gload_lds4(edr + j0s + w * 32 + l, &eds[nb][w][0]);             \
    } while (0)

    STAGE(0, 0);   // issue first stage before the med reduce (latency overlap)

    // block-wide max of ed over all 2048 j (upper bound; cancels in num/den)
    float4 m0 = ((const float4*)edr)[tid * 2];
    float4 m1 = ((const float4*)edr)[tid * 2 + 1];
    float mm = fmaxf(fmaxf(fmaxf(m0.x, m0.y), fmaxf(m0.z, m0.w)),
                     fmaxf(fmaxf(m1.x, m1.y), fmaxf(m1.z, m1.w)));
#pragma unroll
    for (int d = 1; d < 64; d <<= 1) mm = fmaxf(mm, __shfl_xor(mm, d));
    if (l == 0) red[w] = mm;
    __syncthreads();
    const float medf = fmaxf(fmaxf(red[0], red[1]), fmaxf(red[2], red[3]));

    // per-row softmax constants for the two subtiles (log2e-scaled domain)
    const float esvA = es[(long)rbh * NN + i0 + w * 16 + row];
    const float esvB = es[(long)rbh * NN + i0 + 64 + w * 16 + row];
    const float xA = esvA + medf, xB = esvB + medf;
    const float MA = fmaxf(xA, LEAKY * xA), MB = fmaxf(xB, LEAKY * xB);
    const float uA = esvA - MA, vA = fmaf(LEAKY, esvA, -MA);
    const float uB = esvB - MB, vB = fmaf(LEAKY, esvB, -MB);

    f32x4 acc0A = {0,0,0,0}, acc1A = {0,0,0,0}, accDA = {0,0,0,0};
    f32x4 acc0B = {0,0,0,0}, acc1B = {0,0,0,0}, accDB = {0,0,0,0};
    bf16x8 ones;
#pragma unroll
    for (int i = 0; i < 8; ++i) ones[i] = (short)0x3F80;   // bf16 1.0

    for (int s = 0; s < 8; ++s) {
        const int cb = s & 1, nb = cb ^ 1;
        if (s < 7) {
            STAGE(s + 1, nb);
            asm volatile("s_waitcnt vmcnt(5)" ::: "memory");
        } else {
            asm volatile("s_waitcnt vmcnt(0)" ::: "memory");
        }
        __builtin_amdgcn_s_barrier();
        __builtin_amdgcn_sched_barrier(0);

#pragma unroll
        for (int jc = 0; jc < 4; ++jc) {
            bf16x8 b0 = *(const bf16x8*)&whs[cb][jc][kg][row][0];
            bf16x8 b1 = *(const bf16x8*)&whs[cb][jc][kg][row + 16][0];
            float4 e0 = *(const float4*)&eds[cb][jc][kg * 8];
            float4 e1 = *(const float4*)&eds[cb][jc][kg * 8 + 4];
            const unsigned mybA = (bms[cb][jc][w * 16 + row] >> (kg * 8)) & 0xffu;
            const unsigned mybB = (bms[cb][jc][64 + w * 16 + row] >> (kg * 8)) & 0xffu;

            float ev[8];
            ev[0] = e0.x; ev[1] = e0.y; ev[2] = e0.z; ev[3] = e0.w;
            ev[4] = e1.x; ev[5] = e1.y; ev[6] = e1.z; ev[7] = e1.w;

            bf16x8 pA, pB;
#pragma unroll
            for (int c = 0; c < 8; ++c) {
                float pa = __builtin_amdgcn_exp2f(
                    fmaxf(uA + ev[c], fmaf(LEAKY, ev[c], vA)));
                float pb = __builtin_amdgcn_exp2f(
                    fmaxf(uB + ev[c], fmaf(LEAKY, ev[c], vB)));
                const int ma = ((int)(mybA << (31 - c))) >> 31;   // v_bfe_i32
                const int mb = ((int)(mybB << (31 - c))) >> 31;
                pa = __uint_as_float(__float_as_uint(pa) & (unsigned)ma);
                pb = __uint_as_float(__float_as_uint(pb) & (unsigned)mb);
                __hip_bfloat16 ha = __float2bfloat16(pa);
                __hip_bfloat16 hb = __float2bfloat16(pb);
                pA[c] = __builtin_bit_cast(short, ha);
                pB[c] = __builtin_bit_cast(short, hb);
            }

            acc0A = __builtin_amdgcn_mfma_f32_16x16x32_bf16(pA, b0, acc0A, 0, 0, 0);
            acc1A = __builtin_amdgcn_mfma_f32_16x16x32_bf16(pA, b1, acc1A, 0, 0, 0);
            accDA = __builtin_amdgcn_mfma_f32_16x16x32_bf16(pA, ones, accDA, 0, 0, 0);
            acc0B = __builtin_amdgcn_mfma_f32_16x16x32_bf16(pB, b0, acc0B, 0, 0, 0);
            acc1B = __builtin_amdgcn_mfma_f32_16x16x32_bf16(pB, b1, acc1B, 0, 0, 0);
            accDB = __builtin_amdgcn_mfma_f32_16x16x32_bf16(pB, ones, accDB, 0, 0, 0);
        }
        __builtin_amdgcn_s_barrier();
        __builtin_amdgcn_sched_barrier(0);
    }
#undef STAGE

    // epilogue: un-normalized numerators + denominators for both subtiles
    const int fcol = l & 15;
    const int pr = r * 2 + jh;
#pragma unroll
    for (int reg = 0; reg < 4; ++reg) {
        const int orow = (l >> 4) * 4 + reg;
        const long roA = (long)pr * (BB * NN) + (long)b * NN + i0 + w * 16 + orow;
        const long roB = roA + 64;
        num[roA * DD + h * HD + fcol]      = acc0A[reg];
        num[roA * DD + h * HD + 16 + fcol] = acc1A[reg];
        num[roB * DD + h * HD + fcol]      = acc0B[reg];
        num[roB * DD + h * HD + 16 + fcol] = acc1B[reg];
        if (fcol == 0) {
            den[roA * HH + h] = accDA[reg];
            den[roB * HH + h] = accDB[reg];
        }
    }
}

// ---------------------------------------------------------------------------
// Kernel 3: out = LayerNorm(H + mean_r (num_r / den_r)).  One wave per row.
// ---------------------------------------------------------------------------
__global__ __launch_bounds__(256) void finalize_kernel(
    const float* __restrict__ H, const float* __restrict__ num,
    const float* __restrict__ den,
    const float* __restrict__ gamma, const float* __restrict__ beta,
    float* __restrict__ out)
{
    const int w = threadIdx.x >> 6;
    const int l = threadIdx.x & 63;
    const long row = (long)blockIdx.x * 4 + w;    // over B*N rows
    const float2 hv = ((const float2*)(H + row * DD))[l];

    float ax = 0.f, ay = 0.f;
#pragma unroll
    for (int r = 0; r < RR; ++r) {
        float dsum = 0.f, nx = 0.f, ny = 0.f;
#pragma unroll
        for (int j = 0; j < 2; ++j) {
            const long ro = (long)(r * 2 + j) * (BB * NN) + row;
            dsum += den[ro * HH + (l >> 4)];
            const float2 nv = ((const float2*)(num + ro * DD))[l];
            nx += nv.x; ny += nv.y;
        }
        const float inv = (dsum > 0.f) ? 1.0f / dsum : 0.0f;
        ax = fmaf(nx, inv, ax);
        ay = fmaf(ny, inv, ay);
    }
    const float x0 = hv.x + ax * (1.0f / RR);
    const float x1 = hv.y + ay * (1.0f / RR);
    float s = x0 + x1, q = x0 * x0 + x1 * x1;
#pragma unroll
    for (int m = 1; m < 64; m <<= 1) {
        s += __shfl_xor(s, m);
        q += __shfl_xor(q, m);
    }
    const float mu  = s * (1.0f / DD);
    const float var = q * (1.0f / DD) - mu * mu;
    const float inv = rsqrtf(var + LN_EPS);
    const float g0 = gamma[l * 2], g1 = gamma[l * 2 + 1];
    const float b0 = beta[l * 2],  b1 = beta[l * 2 + 1];
    float2 o;
    o.x = (x0 - mu) * inv * g0 + b0;
    o.y = (x1 - mu) * inv * g1 + b1;
    ((float2*)(out + row * DD))[l] = o;
}

// ---------------------------------------------------------------------------
extern "C" void kernel_launch(void* const* d_in, const int* in_sizes, int n_in,
                              void* d_out, int out_size, void* d_ws, size_t ws_size,
                              hipStream_t stream)
{
    const float* H      = (const float*)d_in[0];
    const int*   A      = (const int*)d_in[1];
    const float* W      = (const float*)d_in[2];
    const float* a_src  = (const float*)d_in[3];
    const float* a_dst  = (const float*)d_in[4];
    const float* gamma  = (const float*)d_in[5];
    const float* beta   = (const float*)d_in[6];
    float* out = (float*)d_out;

    // workspace carve (~19.6 MB)
    char* ws = (char*)d_ws;
    float* num = (float*)ws;                     ws += (size_t)RR * 2 * BB * NN * DD * 4;  // 12.6 MB
    float* den = (float*)ws;                     ws += (size_t)RR * 2 * BB * NN * HH * 4;  // 393 KB
    float* es  = (float*)ws;                     ws += (size_t)RR * BB * HH * NN * 4;      // 196 KB
    float* ed  = (float*)ws;                     ws += (size_t)RR * BB * HH * NN * 4;      // 196 KB
    __hip_bfloat16* whT = (__hip_bfloat16*)ws;   ws += (size_t)RR * BB * HH * HD * NN * 2; // 3.15 MB
    unsigned* bmask = (unsigned*)ws;             ws += (size_t)RR * BB * NN * (NN / 32) * 4; // 3.15 MB

    prep_kernel<<<3840, 256, 0, stream>>>(H, A, W, a_src, a_dst, es, ed, whT, bmask);
    gat_attn_kernel<<<RR * BB * HH * 16 * 2, 256, 0, stream>>>(bmask, es, ed, whT, num, den);
    finalize_kernel<<<BB * NN / 4, 256, 0, stream>>>(H, num, den, gamma, beta, out);
}